// Round 17
// baseline (142.981 us; speedup 1.0000x reference)
//
#include <hip/hip_runtime.h>

// Problem constants: B=32, C=768, H=W=24 -> HW=576
#define B_  32
#define C_  768
#define HW_ 576

#define NCQ 18               // HW_/32 k-chunks (qk)
#define NCP 24               // C_/32 k-chunks (pv)

typedef _Float16 half8 __attribute__((ext_vector_type(8)));
typedef _Float16 half4 __attribute__((ext_vector_type(4)));
typedef float    f32x4 __attribute__((ext_vector_type(4)));

__device__ __forceinline__ void g2l16(const void* g, void* l) {
    __builtin_amdgcn_global_load_lds(
        (const __attribute__((address_space(1))) unsigned int*)g,
        (__attribute__((address_space(3))) unsigned int*)l, 16, 0, 0);
}

#define VM(N) asm volatile("s_waitcnt vmcnt(" #N ")" ::: "memory")

// attn is stored LINEARIZED chunk-major (pv's staging layout):
//   float index = ((bz*6 + strip)*24 + chunk)*4096 + row_in_strip*32 + col_in_chunk
// making pv's A-read a fully sequential 16KB-per-chunk stream.

// ---------------------------------------------------------------------------
// prep3: SINGLE DELTA vs round-16 prep_all: the q16/kv16 branch reads f1/f2
// as FULLY SEQUENTIAL 16KB/iteration streams (block = 32-row group of a
// 128-row strip; thread t reads bytes it*16K + t*16), and scatters 8B half4
// stores within the strip's 147KB staged region (L2-resident). Identical
// conversion + layout bytes -> downstream kernels bit-identical.
// vt branch (already coalesced via LDS transpose) unchanged.
// ---------------------------------------------------------------------------
__global__ __launch_bounds__(256) void prep3(const float* __restrict__ f1,
                                             const float* __restrict__ f2,
                                             char* __restrict__ q16,
                                             char* __restrict__ kv16,
                                             char* __restrict__ vt,
                                             int b0, int cur, int nst) {
    __shared__ float Vsh[32 * 201];
    const int bid = blockIdx.x;
    if (bid < nst) {
        // u in [0,24): ti = u>>2 (128-row strip), rg = u&3 (32-row group)
        const int bz = bid % cur, u = bid / cur;
        const int ti = u >> 2, rg = u & 3;
        const float* s1 = f1 + ((size_t)(b0 + bz) * C_ + ti * 128 + rg * 32) * HW_;
        const float* s2 = f2 + ((size_t)(b0 + bz) * C_ + ti * 128 + rg * 32) * HW_;
        char* dq = q16  + ((size_t)(bz * 6 + ti)) * (NCQ * 8192);
        char* dk = kv16 + ((size_t)(bz * 6 + ti)) * (NCQ * 8192);
        #pragma unroll
        for (int it = 0; it < 18; ++it) {
            int g     = it * 1024 + threadIdx.x * 4;   // float index in 32x576 group
            int row_l = g / 576;
            int col   = g - row_l * 576;
            int row   = rg * 32 + row_l;
            int k0    = col >> 5, kk = col & 31;       // kk in {0,4,...,28}
            int x     = (kk >> 3) ^ ((row >> 1) & 3);
            size_t doff = (size_t)k0 * 8192 + row * 64 + x * 16 + (kk & 7) * 2;
            f32x4 v1 = *(const f32x4*)(s1 + g);
            f32x4 v2 = *(const f32x4*)(s2 + g);
            half4 h1, h2;
            #pragma unroll
            for (int e = 0; e < 4; ++e) {
                h1[e] = (_Float16)v1[e];
                h2[e] = (_Float16)v2[e];
            }
            *(half4*)(dq + doff) = h1;
            *(half4*)(dk + doff) = h2;
        }
    } else {
        int bid2 = bid - nst;
        const int bz = bid2 % cur, u = bid2 / cur;      // u in [0,72)
        int k0 = u / 3, tj = u % 3;
        int b  = b0 + bz;
        int t  = threadIdx.x;
        #pragma unroll
        for (int p = 0; p < 6; ++p) {
            int fidx = p * 256 + t;
            int dd = fidx / 48, c4 = fidx % 48;
            f32x4 v = *(const f32x4*)(f2 + ((size_t)b * C_ + k0 * 32 + dd) * HW_ + tj * 192 + c4 * 4);
            #pragma unroll
            for (int e = 0; e < 4; ++e) Vsh[dd * 201 + c4 * 4 + e] = v[e];
        }
        __syncthreads();
        char* ob = vt + ((size_t)(bz * 3 + tj) * NCP + k0) * 12288;
        #pragma unroll
        for (int p = 0; p < 3; ++p) {
            int o = p * 256 + t;
            int x = o & 3, n = o >> 2;
            int kc = x ^ ((n >> 1) & 3);
            half8 h;
            #pragma unroll
            for (int j = 0; j < 8; ++j) h[j] = (_Float16)Vsh[(kc * 8 + j) * 201 + n];
            *(half8*)(ob + o * 16) = h;
        }
    }
}

// ---------------------------------------------------------------------------
// qk6: attn = q @ kv^T. Tile 192x192, 8 waves (4Mx2N), BK=32, ring-3,
// depth-2 counted-vmcnt pipeline. Epilogue: linearized chunk-major attn
// write + fp32 softmax partials (8 race-free slots per row). (round-16 exact)
// ---------------------------------------------------------------------------
__global__ __launch_bounds__(512, 4) void qk6(const char* __restrict__ q16,
                                              const char* __restrict__ kv16,
                                              float* __restrict__ attn,
                                              float2* __restrict__ part,
                                              int cur) {
    __shared__ __align__(16) char S[3][24576];
    const int wg = blockIdx.x;
    const int bz = wg % cur, u = wg / cur;   // u in [0,16)
    const int ti = u >> 2, tj = u & 3;
    const int t = threadIdx.x, lane = t & 63, w = t >> 6;
    const int rsub = lane >> 2, cb = (lane & 3) * 16;

    const char *p0, *p1, *p2;
    int o0, o1, o2;
    {
        auto arow = [&](int l) {
            int gr = ti * 192 + 16 * l + rsub;
            return q16 + ((size_t)(bz * 6 + (gr >> 7)) * NCQ) * 8192 + (gr & 127) * 64 + cb;
        };
        auto brow = [&](int l) {
            int gd = tj * 192 + 16 * l + rsub;
            return kv16 + ((size_t)(bz * 6 + (gd >> 7)) * NCQ) * 8192 + (gd & 127) * 64 + cb;
        };
        if (w < 4) {
            p0 = arow(2 * w);     o0 = (2 * w) * 1024;
            p1 = arow(2 * w + 1); o1 = (2 * w + 1) * 1024;
            p2 = brow(8 + w);     o2 = 12288 + (8 + w) * 1024;
        } else {
            int v = w - 4;
            p0 = brow(2 * v);     o0 = 12288 + (2 * v) * 1024;
            p1 = brow(2 * v + 1); o1 = 12288 + (2 * v + 1) * 1024;
            p2 = arow(8 + v);     o2 = (8 + v) * 1024;
        }
    }

    const int wr = (w >> 1) * 48, wc = (w & 1) * 96;
    const int r16 = lane & 15, cg = lane >> 4;
    int offA[3], offB[6];
    #pragma unroll
    for (int m = 0; m < 3; ++m) {
        int ra = wr + m * 16 + r16;
        offA[m] = ra * 64 + ((cg ^ ((ra >> 1) & 3)) << 4);
    }
    #pragma unroll
    for (int n = 0; n < 6; ++n) {
        int rb = wc + n * 16 + r16;
        offB[n] = 12288 + rb * 64 + ((cg ^ ((rb >> 1) & 3)) << 4);
    }

    f32x4 acc[3][6] = {};

#define STG(SLOT) do {                          \
        char* sb_ = &S[SLOT][0];                \
        g2l16(p0, sb_ + o0);                    \
        g2l16(p1, sb_ + o1);                    \
        g2l16(p2, sb_ + o2);                    \
        p0 += 8192; p1 += 8192; p2 += 8192;     \
    } while (0)

    STG(0); STG(1);
    int rd = 0, st = 2;
    for (int c = 0; c < NCQ; ++c) {
        if (c + 2 < NCQ) {
            STG(st); st = (st == 2) ? 0 : st + 1;
            VM(6);
        } else if (c + 2 == NCQ) {
            VM(3);
        } else {
            VM(0);
        }
        __builtin_amdgcn_s_barrier();
        const char* sb = &S[rd][0];
        rd = (rd == 2) ? 0 : rd + 1;
        half8 a0 = *(const half8*)(sb + offA[0]);
        half8 a1 = *(const half8*)(sb + offA[1]);
        half8 a2 = *(const half8*)(sb + offA[2]);
        __builtin_amdgcn_s_setprio(1);
        #pragma unroll
        for (int n = 0; n < 6; ++n) {
            half8 bn = *(const half8*)(sb + offB[n]);
            acc[0][n] = __builtin_amdgcn_mfma_f32_16x16x32_f16(a0, bn, acc[0][n], 0, 0, 0);
            acc[1][n] = __builtin_amdgcn_mfma_f32_16x16x32_f16(a1, bn, acc[1][n], 0, 0, 0);
            acc[2][n] = __builtin_amdgcn_mfma_f32_16x16x32_f16(a2, bn, acc[2][n], 0, 0, 0);
        }
        __builtin_amdgcn_s_setprio(0);
        __builtin_amdgcn_s_barrier();
    }
#undef STG

    // epilogue: linearized chunk-major attn write
    const int col = lane & 15, rbase = (lane >> 4) * 4;
    #pragma unroll
    for (int m = 0; m < 3; ++m)
        #pragma unroll
        for (int n = 0; n < 6; ++n)
            #pragma unroll
            for (int rg = 0; rg < 4; ++rg) {
                int grow = ti * 192 + wr + m * 16 + rbase + rg;
                int gcol = tj * 192 + wc + n * 16 + col;
                attn[(((size_t)bz * 6 + (grow >> 7)) * NCP + (gcol >> 5)) * 4096
                     + (grow & 127) * 32 + (gcol & 31)] = acc[m][n][rg];
            }

    // per-(row, 96-col half) softmax partials; slot = tj*2 + (w&1).
    const int half = w & 1;
    #pragma unroll
    for (int m = 0; m < 3; ++m)
        #pragma unroll
        for (int rg = 0; rg < 4; ++rg) {
            float mx = -1e30f;
            #pragma unroll
            for (int n = 0; n < 6; ++n) mx = fmaxf(mx, acc[m][n][rg]);
            #pragma unroll
            for (int o = 1; o < 16; o <<= 1) mx = fmaxf(mx, __shfl_xor(mx, o));
            float s = 0.f;
            #pragma unroll
            for (int n = 0; n < 6; ++n) s += __expf(acc[m][n][rg] - mx);
            #pragma unroll
            for (int o = 1; o < 16; o <<= 1) s += __shfl_xor(s, o);
            if ((lane & 15) == 0) {
                int row = wr + m * 16 + (lane >> 4) * 4 + rg;
                part[((size_t)bz * C_ + ti * 192 + row) * 8 + tj * 2 + half] =
                    make_float2(mx, s);
            }
        }
}

// ---------------------------------------------------------------------------
// pv10: out = (gamma*P)@V + feat1, softmax fused into A-staging. Paired
// chunks (12 phases of 2), ring-4 of 20KB slots, linearized attn A-stream,
// folded sm_combine. Plain stores for out (NT reverted: round-16 showed NT
// forces partial-line HBM writebacks, WRITE 55->70 MB, +3 us).
// ---------------------------------------------------------------------------
__global__ __launch_bounds__(512, 4) void pv10(const float* __restrict__ attn,
                                               const char* __restrict__ vt,
                                               const float2* __restrict__ part,
                                               const float* __restrict__ gamma,
                                               const float* __restrict__ f1,
                                               float* __restrict__ out,
                                               int b0, int cur) {
    __shared__ __align__(16) char S[4][20480];   // per slot: A 8KB | B 12KB
    const int wg = blockIdx.x;
    const int bz = wg % cur, u = wg / cur;       // u in [0,18)
    const int ti = u / 3, tj = u % 3;
    const int t = threadIdx.x, lane = t & 63, w = t >> 6;
    const int rsub = lane >> 2, cbb = (lane & 3) * 16;

    // ---- A staging: thread t owns row r0, k-group g4 (8 cols) per chunk ----
    const int r0 = t >> 2;            // row 0..127
    const int g4 = t & 3;             // 16B k-group within 32-col chunk
    const float* srcA = attn + (((size_t)bz * 6 + ti) * NCP) * 4096 + t * 8;
    const int aw0 = r0 * 64 + ((g4 ^ ((r0 >> 1) & 3)) << 4);

    // ---- stats: folded sm_combine (identical reduction order) ----
    float2 ms0;
    {
        const float2* pr = part + ((size_t)bz * C_ + ti * 128 + r0) * 8;
        float2 p8[8];
        #pragma unroll
        for (int i = 0; i < 8; ++i) p8[i] = pr[i];
        float m = p8[0].x;
        #pragma unroll
        for (int i = 1; i < 8; ++i) m = fmaxf(m, p8[i].x);
        float s = 0.f;
        #pragma unroll
        for (int i = 0; i < 8; ++i) s += p8[i].y * __expf(p8[i].x - m);
        ms0 = make_float2(m, gamma[0] / s);
    }

    // ---- B staging (g2l) ----
    const char* vbase = vt + ((size_t)(bz * 3 + tj) * NCP) * 12288;
    const char *pB0, *pB1;
    int ob0, ob1;
    if (w < 4) {
        pB0 = vbase + (32 * w + rsub) * 64 + cbb;          ob0 = 8192 + (32 * w) * 64;
        pB1 = vbase + (32 * w + 16 + rsub) * 64 + cbb;     ob1 = 8192 + (32 * w + 16) * 64;
    } else {
        pB0 = vbase + (128 + 16 * (w - 4) + rsub) * 64 + cbb;
        ob0 = 8192 + (128 + 16 * (w - 4)) * 64;
        pB1 = vbase; ob1 = 0;  // unused
    }

    const int wr = (w >> 2) * 64, wc = (w & 3) * 48;
    const int r16 = lane & 15, cg = lane >> 4;
    int offA[4], offB[3];
    #pragma unroll
    for (int m = 0; m < 4; ++m) {
        int ra = wr + m * 16 + r16;
        offA[m] = ra * 64 + ((cg ^ ((ra >> 1) & 3)) << 4);
    }
    #pragma unroll
    for (int n = 0; n < 3; ++n) {
        int rb = wc + n * 16 + r16;
        offB[n] = 8192 + rb * 64 + ((cg ^ ((rb >> 1) & 3)) << 4);
    }

    f32x4 acc[4][3] = {};
    f32x4 vaA0, vaA1;    // named set A (even chunk of pair)
    f32x4 vaB0, vaB1;    // named set B (odd  chunk of pair)

#define STG_B(SLOT) do {                                  \
        g2l16(pB0, &S[SLOT][0] + ob0); pB0 += 12288;      \
        if (w < 4) { g2l16(pB1, &S[SLOT][0] + ob1); pB1 += 12288; } \
    } while (0)
#define LD_A(V0, V1) do { V0 = *(const f32x4*)srcA; V1 = *(const f32x4*)(srcA + 4); \
                          srcA += 4096; } while (0)
#define WR_A(SLOT, V0, V1) do {                                        \
        half8 h_;                                                      \
        _Pragma("unroll")                                              \
        for (int e = 0; e < 4; ++e) {                                  \
            h_[e]     = (_Float16)(__expf(V0[e] - ms0.x) * ms0.y);     \
            h_[4 + e] = (_Float16)(__expf(V1[e] - ms0.x) * ms0.y);     \
        }                                                              \
        *(half8*)(&S[SLOT][0] + aw0) = h_;                             \
    } while (0)
#define MFMA_SLOT(SB) do {                                             \
        const char* sb_ = (SB);                                        \
        half8 a_[4], b_[3];                                            \
        _Pragma("unroll")                                              \
        for (int m = 0; m < 4; ++m) a_[m] = *(const half8*)(sb_ + offA[m]); \
        _Pragma("unroll")                                              \
        for (int n = 0; n < 3; ++n) b_[n] = *(const half8*)(sb_ + offB[n]); \
        _Pragma("unroll")                                              \
        for (int m = 0; m < 4; ++m)                                    \
            _Pragma("unroll")                                          \
            for (int n = 0; n < 3; ++n)                                \
                acc[m][n] = __builtin_amdgcn_mfma_f32_16x16x32_f16(a_[m], b_[n], acc[m][n], 0, 0, 0); \
    } while (0)

    // prologue: A(0)->slot0, A(1)->slot1; B(0)->slot0, B(1)->slot1;
    // preload A(2)->setA, A(3)->setB.
    LD_A(vaA0, vaA1);
    WR_A(0, vaA0, vaA1);
    LD_A(vaB0, vaB1);
    WR_A(1, vaB0, vaB1);
    STG_B(0); STG_B(1);
    LD_A(vaA0, vaA1);        // chunk 2
    LD_A(vaB0, vaB1);        // chunk 3

    for (int p = 0; p < 12; ++p) {
        const int sa = (2 * p) & 3;          // slot of chunk 2p
        asm volatile("s_waitcnt lgkmcnt(0)" ::: "memory");
        __builtin_amdgcn_s_barrier();
        if (p < 11) { STG_B((sa + 2) & 3); STG_B((sa + 3) & 3); }
        if (p < 11) { if (w < 4) VM(8); else VM(6); }
        else        { VM(0); }
        __builtin_amdgcn_s_barrier();

        __builtin_amdgcn_s_setprio(1);
        MFMA_SLOT(&S[sa][0]);
        MFMA_SLOT(&S[sa ^ 1][0]);            // slot of chunk 2p+1
        __builtin_amdgcn_s_setprio(0);

        if (p < 11) {
            WR_A((sa + 2) & 3, vaA0, vaA1);  // chunk 2p+2
            WR_A((sa + 3) & 3, vaB0, vaB1);  // chunk 2p+3
            if (p < 10) {
                LD_A(vaA0, vaA1);            // chunk 2p+4
                LD_A(vaB0, vaB1);            // chunk 2p+5
            }
        }
    }
#undef MFMA_SLOT
#undef WR_A
#undef LD_A
#undef STG_B

    const int b = b0 + bz;
    const float* f1b = f1 + ((size_t)b * C_ + ti * 128) * HW_ + tj * 192;
    float*       ob  = out + ((size_t)b * C_ + ti * 128) * HW_ + tj * 192;
    const int col = lane & 15, rbase = (lane >> 4) * 4;
    #pragma unroll
    for (int m = 0; m < 4; ++m)
        #pragma unroll
        for (int n = 0; n < 3; ++n)
            #pragma unroll
            for (int rg = 0; rg < 4; ++rg) {
                int r2 = wr + m * 16 + rbase + rg;
                int c2 = wc + n * 16 + col;
                ob[(size_t)r2 * HW_ + c2] = acc[m][n][rg] + f1b[(size_t)r2 * HW_ + c2];
            }
}

// ---------------------------------------------------------------------------
extern "C" void kernel_launch(void* const* d_in, const int* in_sizes, int n_in,
                              void* d_out, int out_size, void* d_ws, size_t ws_size,
                              hipStream_t stream) {
    const float* feat1 = (const float*)d_in[0];
    const float* feat2 = (const float*)d_in[1];
    const float* gamma = (const float*)d_in[2];
    float* out = (float*)d_out;

    const size_t SZ_Q    = (size_t)C_ * HW_ * 2;      //   884,736 B/batch
    const size_t SZ_ATTN = (size_t)C_ * C_  * 4;      // 2,359,296 B/batch (fp32)
    const size_t SZ_PART = (size_t)C_ * 8 * 8;        //    49,152 B/batch
    const size_t per_batch = SZ_ATTN + 3 * SZ_Q + SZ_PART;

    int nb = (int)(ws_size / per_batch);
    if (nb < 1) nb = 1;
    if (nb > B_) nb = B_;

    char* ws     = (char*)d_ws;
    float* attn  = (float*)ws;
    char* q16    = ws + (size_t)nb * SZ_ATTN;
    char* kv16   = q16 + (size_t)nb * SZ_Q;
    char* vtb    = kv16 + (size_t)nb * SZ_Q;
    float2* part = (float2*)(vtb + (size_t)nb * SZ_Q);

    for (int b0 = 0; b0 < B_; b0 += nb) {
        int cur = (B_ - b0 < nb) ? (B_ - b0) : nb;
        prep3<<<cur * 96, 256, 0, stream>>>(feat1, feat2, q16, kv16, vtb, b0, cur, cur * 24);
        qk6<<<cur * 16, 512, 0, stream>>>(q16, kv16, attn, part, cur);
        pv10<<<cur * 18, 512, 0, stream>>>(attn, vtb, part, gamma, feat1, out, b0, cur);
    }
}

// Round 18
// 127.356 us; speedup vs baseline: 1.1227x; 1.1227x over previous
//
#include <hip/hip_runtime.h>

// Problem constants: B=32, C=768, H=W=24 -> HW=576
#define B_  32
#define C_  768
#define HW_ 576

#define NCQ 18               // HW_/32 k-chunks (qk)
#define NCP 24               // C_/32 k-chunks (pv)

typedef _Float16 half8 __attribute__((ext_vector_type(8)));
typedef _Float16 half4 __attribute__((ext_vector_type(4)));
typedef float    f32x4 __attribute__((ext_vector_type(4)));

__device__ __forceinline__ void g2l16(const void* g, void* l) {
    __builtin_amdgcn_global_load_lds(
        (const __attribute__((address_space(1))) unsigned int*)g,
        (__attribute__((address_space(3))) unsigned int*)l, 16, 0, 0);
}

#define VM(N) asm volatile("s_waitcnt vmcnt(" #N ")" ::: "memory")

// attnE holds exp(S - mx_half) in fp16, LINEARIZED chunk-major:
//   elem index = ((bz*6 + strip)*24 + chunk)*4096 + row_in_strip*32 + col_in_chunk
// (strip = row>>7, chunk = col>>5). Values in [0,1] -> fp16-safe (rel 2^-11).
// pv rescales by exp(mx_half - m_row)*gamma/s_row per (row, 96-col half).

// ---------------------------------------------------------------------------
// prep3: q16/kv16 sequential-read staging + vt LDS-transpose. (round-17 exact)
// ---------------------------------------------------------------------------
__global__ __launch_bounds__(256) void prep3(const float* __restrict__ f1,
                                             const float* __restrict__ f2,
                                             char* __restrict__ q16,
                                             char* __restrict__ kv16,
                                             char* __restrict__ vt,
                                             int b0, int cur, int nst) {
    __shared__ float Vsh[32 * 201];
    const int bid = blockIdx.x;
    if (bid < nst) {
        const int bz = bid % cur, u = bid / cur;
        const int ti = u >> 2, rg = u & 3;
        const float* s1 = f1 + ((size_t)(b0 + bz) * C_ + ti * 128 + rg * 32) * HW_;
        const float* s2 = f2 + ((size_t)(b0 + bz) * C_ + ti * 128 + rg * 32) * HW_;
        char* dq = q16  + ((size_t)(bz * 6 + ti)) * (NCQ * 8192);
        char* dk = kv16 + ((size_t)(bz * 6 + ti)) * (NCQ * 8192);
        #pragma unroll
        for (int it = 0; it < 18; ++it) {
            int g     = it * 1024 + threadIdx.x * 4;
            int row_l = g / 576;
            int col   = g - row_l * 576;
            int row   = rg * 32 + row_l;
            int k0    = col >> 5, kk = col & 31;
            int x     = (kk >> 3) ^ ((row >> 1) & 3);
            size_t doff = (size_t)k0 * 8192 + row * 64 + x * 16 + (kk & 7) * 2;
            f32x4 v1 = *(const f32x4*)(s1 + g);
            f32x4 v2 = *(const f32x4*)(s2 + g);
            half4 h1, h2;
            #pragma unroll
            for (int e = 0; e < 4; ++e) {
                h1[e] = (_Float16)v1[e];
                h2[e] = (_Float16)v2[e];
            }
            *(half4*)(dq + doff) = h1;
            *(half4*)(dk + doff) = h2;
        }
    } else {
        int bid2 = bid - nst;
        const int bz = bid2 % cur, u = bid2 / cur;
        int k0 = u / 3, tj = u % 3;
        int b  = b0 + bz;
        int t  = threadIdx.x;
        #pragma unroll
        for (int p = 0; p < 6; ++p) {
            int fidx = p * 256 + t;
            int dd = fidx / 48, c4 = fidx % 48;
            f32x4 v = *(const f32x4*)(f2 + ((size_t)b * C_ + k0 * 32 + dd) * HW_ + tj * 192 + c4 * 4);
            #pragma unroll
            for (int e = 0; e < 4; ++e) Vsh[dd * 201 + c4 * 4 + e] = v[e];
        }
        __syncthreads();
        char* ob = vt + ((size_t)(bz * 3 + tj) * NCP + k0) * 12288;
        #pragma unroll
        for (int p = 0; p < 3; ++p) {
            int o = p * 256 + t;
            int x = o & 3, n = o >> 2;
            int kc = x ^ ((n >> 1) & 3);
            half8 h;
            #pragma unroll
            for (int j = 0; j < 8; ++j) h[j] = (_Float16)Vsh[(kc * 8 + j) * 201 + n];
            *(half8*)(ob + o * 16) = h;
        }
    }
}

// ---------------------------------------------------------------------------
// qk6: S = q @ kv^T. Tile 192x192, 8 waves (4Mx2N), BK=32, ring-3, depth-2
// counted-vmcnt pipeline. Epilogue: per-(row,96-col-half) partials {mx,s}
// (bit-identical to prior rounds) + attnE = fp16 exp(S - mx_half), reusing
// the partials' max. Halves attn bytes and removes pv's expf work.
// ---------------------------------------------------------------------------
__global__ __launch_bounds__(512, 4) void qk6(const char* __restrict__ q16,
                                              const char* __restrict__ kv16,
                                              _Float16* __restrict__ attnE,
                                              float2* __restrict__ part,
                                              int cur) {
    __shared__ __align__(16) char S[3][24576];
    const int wg = blockIdx.x;
    const int bz = wg % cur, u = wg / cur;   // u in [0,16)
    const int ti = u >> 2, tj = u & 3;
    const int t = threadIdx.x, lane = t & 63, w = t >> 6;
    const int rsub = lane >> 2, cb = (lane & 3) * 16;

    const char *p0, *p1, *p2;
    int o0, o1, o2;
    {
        auto arow = [&](int l) {
            int gr = ti * 192 + 16 * l + rsub;
            return q16 + ((size_t)(bz * 6 + (gr >> 7)) * NCQ) * 8192 + (gr & 127) * 64 + cb;
        };
        auto brow = [&](int l) {
            int gd = tj * 192 + 16 * l + rsub;
            return kv16 + ((size_t)(bz * 6 + (gd >> 7)) * NCQ) * 8192 + (gd & 127) * 64 + cb;
        };
        if (w < 4) {
            p0 = arow(2 * w);     o0 = (2 * w) * 1024;
            p1 = arow(2 * w + 1); o1 = (2 * w + 1) * 1024;
            p2 = brow(8 + w);     o2 = 12288 + (8 + w) * 1024;
        } else {
            int v = w - 4;
            p0 = brow(2 * v);     o0 = 12288 + (2 * v) * 1024;
            p1 = brow(2 * v + 1); o1 = 12288 + (2 * v + 1) * 1024;
            p2 = arow(8 + v);     o2 = (8 + v) * 1024;
        }
    }

    const int wr = (w >> 1) * 48, wc = (w & 1) * 96;
    const int r16 = lane & 15, cg = lane >> 4;
    int offA[3], offB[6];
    #pragma unroll
    for (int m = 0; m < 3; ++m) {
        int ra = wr + m * 16 + r16;
        offA[m] = ra * 64 + ((cg ^ ((ra >> 1) & 3)) << 4);
    }
    #pragma unroll
    for (int n = 0; n < 6; ++n) {
        int rb = wc + n * 16 + r16;
        offB[n] = 12288 + rb * 64 + ((cg ^ ((rb >> 1) & 3)) << 4);
    }

    f32x4 acc[3][6] = {};

#define STG(SLOT) do {                          \
        char* sb_ = &S[SLOT][0];                \
        g2l16(p0, sb_ + o0);                    \
        g2l16(p1, sb_ + o1);                    \
        g2l16(p2, sb_ + o2);                    \
        p0 += 8192; p1 += 8192; p2 += 8192;     \
    } while (0)

    STG(0); STG(1);
    int rd = 0, st = 2;
    for (int c = 0; c < NCQ; ++c) {
        if (c + 2 < NCQ) {
            STG(st); st = (st == 2) ? 0 : st + 1;
            VM(6);
        } else if (c + 2 == NCQ) {
            VM(3);
        } else {
            VM(0);
        }
        __builtin_amdgcn_s_barrier();
        const char* sb = &S[rd][0];
        rd = (rd == 2) ? 0 : rd + 1;
        half8 a0 = *(const half8*)(sb + offA[0]);
        half8 a1 = *(const half8*)(sb + offA[1]);
        half8 a2 = *(const half8*)(sb + offA[2]);
        __builtin_amdgcn_s_setprio(1);
        #pragma unroll
        for (int n = 0; n < 6; ++n) {
            half8 bn = *(const half8*)(sb + offB[n]);
            acc[0][n] = __builtin_amdgcn_mfma_f32_16x16x32_f16(a0, bn, acc[0][n], 0, 0, 0);
            acc[1][n] = __builtin_amdgcn_mfma_f32_16x16x32_f16(a1, bn, acc[1][n], 0, 0, 0);
            acc[2][n] = __builtin_amdgcn_mfma_f32_16x16x32_f16(a2, bn, acc[2][n], 0, 0, 0);
        }
        __builtin_amdgcn_s_setprio(0);
        __builtin_amdgcn_s_barrier();
    }
#undef STG

    // --- partials first (captures mx per (m,rg); path bit-identical) ---
    const int half = w & 1;
    float mxv[3][4];                 // static-indexed only
    #pragma unroll
    for (int m = 0; m < 3; ++m)
        #pragma unroll
        for (int rg = 0; rg < 4; ++rg) {
            float mx = -1e30f;
            #pragma unroll
            for (int n = 0; n < 6; ++n) mx = fmaxf(mx, acc[m][n][rg]);
            #pragma unroll
            for (int o = 1; o < 16; o <<= 1) mx = fmaxf(mx, __shfl_xor(mx, o));
            mxv[m][rg] = mx;
            float s = 0.f;
            #pragma unroll
            for (int n = 0; n < 6; ++n) s += __expf(acc[m][n][rg] - mx);
            #pragma unroll
            for (int o = 1; o < 16; o <<= 1) s += __shfl_xor(s, o);
            if ((lane & 15) == 0) {
                int row = wr + m * 16 + (lane >> 4) * 4 + rg;
                part[((size_t)bz * C_ + ti * 192 + row) * 8 + tj * 2 + half] =
                    make_float2(mx, s);
            }
        }

    // --- attnE write: fp16 exp(S - mx_half), linearized chunk-major ---
    const int col = lane & 15, rbase = (lane >> 4) * 4;
    #pragma unroll
    for (int m = 0; m < 3; ++m)
        #pragma unroll
        for (int n = 0; n < 6; ++n)
            #pragma unroll
            for (int rg = 0; rg < 4; ++rg) {
                int grow = ti * 192 + wr + m * 16 + rbase + rg;
                int gcol = tj * 192 + wc + n * 16 + col;
                attnE[(((size_t)bz * 6 + (grow >> 7)) * NCP + (gcol >> 5)) * 4096
                      + (grow & 127) * 32 + (gcol & 31)] =
                    (_Float16)__expf(acc[m][n][rg] - mxv[m][rg]);
            }
}

// ---------------------------------------------------------------------------
// pv11: out = (gamma*P)@V + feat1. Paired chunks (12 phases, FULLY UNROLLED
// so per-chunk half-index is compile-time), ring-4 of {A 8KB | B 12KB} slots.
// A-path: load half8 exp-values (sequential stream), scale by per-(row,half)
// factor exp(mx_h - m)*gamma/s, ds_write. No expf in the hot loop beyond the
// one scalar factor per chunk.
// ---------------------------------------------------------------------------
__global__ __launch_bounds__(512, 4) void pv11(const _Float16* __restrict__ attnE,
                                               const char* __restrict__ vt,
                                               const float2* __restrict__ part,
                                               const float* __restrict__ gamma,
                                               const float* __restrict__ f1,
                                               float* __restrict__ out,
                                               int b0, int cur) {
    __shared__ __align__(16) char S[4][20480];   // per slot: A 8KB | B 12KB
    const int wg = blockIdx.x;
    const int bz = wg % cur, u = wg / cur;       // u in [0,18)
    const int ti = u / 3, tj = u % 3;
    const int t = threadIdx.x, lane = t & 63, w = t >> 6;
    const int rsub = lane >> 2, cbb = (lane & 3) * 16;

    // ---- A staging: thread t owns row r0=t>>2, 16B k-group g4=t&3 ----
    const int r0 = t >> 2;
    const int g4 = t & 3;
    const char* srcA = (const char*)(attnE + (((size_t)bz * 6 + ti) * NCP) * 4096) + t * 16;
    const int aw0 = r0 * 64 + ((g4 ^ ((r0 >> 1) & 3)) << 4);

    // ---- stats: global m, inv, and 8 per-half rescale factors ----
    float2 pm[8];                    // constant-indexed after unroll
    float m_row, inv;
    {
        const float2* pr = part + ((size_t)bz * C_ + ti * 128 + r0) * 8;
        #pragma unroll
        for (int i = 0; i < 8; ++i) pm[i] = pr[i];
        float m = pm[0].x;
        #pragma unroll
        for (int i = 1; i < 8; ++i) m = fmaxf(m, pm[i].x);
        float s = 0.f;
        #pragma unroll
        for (int i = 0; i < 8; ++i) s += pm[i].y * __expf(pm[i].x - m);
        m_row = m;
        inv = gamma[0] / s;
    }

    // ---- B staging (g2l) ----
    const char* vbase = vt + ((size_t)(bz * 3 + tj) * NCP) * 12288;
    const char *pB0, *pB1;
    int ob0, ob1;
    if (w < 4) {
        pB0 = vbase + (32 * w + rsub) * 64 + cbb;          ob0 = 8192 + (32 * w) * 64;
        pB1 = vbase + (32 * w + 16 + rsub) * 64 + cbb;     ob1 = 8192 + (32 * w + 16) * 64;
    } else {
        pB0 = vbase + (128 + 16 * (w - 4) + rsub) * 64 + cbb;
        ob0 = 8192 + (128 + 16 * (w - 4)) * 64;
        pB1 = vbase; ob1 = 0;  // unused
    }

    const int wr = (w >> 2) * 64, wc = (w & 3) * 48;
    const int r16 = lane & 15, cg = lane >> 4;
    int offA[4], offB[3];
    #pragma unroll
    for (int m = 0; m < 4; ++m) {
        int ra = wr + m * 16 + r16;
        offA[m] = ra * 64 + ((cg ^ ((ra >> 1) & 3)) << 4);
    }
    #pragma unroll
    for (int n = 0; n < 3; ++n) {
        int rb = wc + n * 16 + r16;
        offB[n] = 8192 + rb * 64 + ((cg ^ ((rb >> 1) & 3)) << 4);
    }

    f32x4 acc[4][3] = {};
    half8 vaA, vaB;      // named A-sets (even/odd chunk of pair)

#define STG_B(SLOT) do {                                  \
        g2l16(pB0, &S[SLOT][0] + ob0); pB0 += 12288;      \
        if (w < 4) { g2l16(pB1, &S[SLOT][0] + ob1); pB1 += 12288; } \
    } while (0)
#define LD_A(V) do { V = *(const half8*)srcA; srcA += 8192; } while (0)
#define WR_A(SLOT, V, H) do {                                          \
        const float fac_ = __expf(pm[H].x - m_row) * inv;              \
        half8 h_;                                                      \
        _Pragma("unroll")                                              \
        for (int e = 0; e < 8; ++e)                                    \
            h_[e] = (_Float16)((float)V[e] * fac_);                    \
        *(half8*)(&S[SLOT][0] + aw0) = h_;                             \
    } while (0)
#define MFMA_SLOT(SB) do {                                             \
        const char* sb_ = (SB);                                        \
        half8 a_[4], b_[3];                                            \
        _Pragma("unroll")                                              \
        for (int m = 0; m < 4; ++m) a_[m] = *(const half8*)(sb_ + offA[m]); \
        _Pragma("unroll")                                              \
        for (int n = 0; n < 3; ++n) b_[n] = *(const half8*)(sb_ + offB[n]); \
        _Pragma("unroll")                                              \
        for (int m = 0; m < 4; ++m)                                    \
            _Pragma("unroll")                                          \
            for (int n = 0; n < 3; ++n)                                \
                acc[m][n] = __builtin_amdgcn_mfma_f32_16x16x32_f16(a_[m], b_[n], acc[m][n], 0, 0, 0); \
    } while (0)

    // prologue: chunks 0,1 -> slots 0,1 (ds_write); B(0),B(1) g2l;
    // preload chunks 2,3 into the register sets.
    LD_A(vaA);
    WR_A(0, vaA, 0);
    LD_A(vaB);
    WR_A(1, vaB, 0);
    STG_B(0); STG_B(1);
    LD_A(vaA);               // chunk 2
    LD_A(vaB);               // chunk 3

    #pragma unroll
    for (int p = 0; p < 12; ++p) {
        const int sa = (2 * p) & 3;          // slot of chunk 2p
        asm volatile("s_waitcnt lgkmcnt(0)" ::: "memory");
        __builtin_amdgcn_s_barrier();
        if (p < 11) { STG_B((sa + 2) & 3); STG_B((sa + 3) & 3); }
        if (p < 11) { if (w < 4) VM(6); else VM(4); }
        else        { VM(0); }
        __builtin_amdgcn_s_barrier();

        __builtin_amdgcn_s_setprio(1);
        MFMA_SLOT(&S[sa][0]);
        MFMA_SLOT(&S[sa ^ 1][0]);            // slot of chunk 2p+1
        __builtin_amdgcn_s_setprio(0);

        if (p < 11) {
            WR_A((sa + 2) & 3, vaA, (2 * p + 2) / 3);   // chunk 2p+2
            WR_A((sa + 3) & 3, vaB, (2 * p + 3) / 3);   // chunk 2p+3
            if (p < 10) {
                LD_A(vaA);                   // chunk 2p+4
                LD_A(vaB);                   // chunk 2p+5
            }
        }
    }
#undef MFMA_SLOT
#undef WR_A
#undef LD_A
#undef STG_B

    const int b = b0 + bz;
    const float* f1b = f1 + ((size_t)b * C_ + ti * 128) * HW_ + tj * 192;
    float*       ob  = out + ((size_t)b * C_ + ti * 128) * HW_ + tj * 192;
    const int col = lane & 15, rbase = (lane >> 4) * 4;
    #pragma unroll
    for (int m = 0; m < 4; ++m)
        #pragma unroll
        for (int n = 0; n < 3; ++n)
            #pragma unroll
            for (int rg = 0; rg < 4; ++rg) {
                int r2 = wr + m * 16 + rbase + rg;
                int c2 = wc + n * 16 + col;
                ob[(size_t)r2 * HW_ + c2] = acc[m][n][rg] + f1b[(size_t)r2 * HW_ + c2];
            }
}

// ---------------------------------------------------------------------------
extern "C" void kernel_launch(void* const* d_in, const int* in_sizes, int n_in,
                              void* d_out, int out_size, void* d_ws, size_t ws_size,
                              hipStream_t stream) {
    const float* feat1 = (const float*)d_in[0];
    const float* feat2 = (const float*)d_in[1];
    const float* gamma = (const float*)d_in[2];
    float* out = (float*)d_out;

    const size_t SZ_Q    = (size_t)C_ * HW_ * 2;      //   884,736 B/batch
    const size_t SZ_ATTN = (size_t)C_ * C_  * 2;      // 1,179,648 B/batch (fp16 exp)
    const size_t SZ_PART = (size_t)C_ * 8 * 8;        //    49,152 B/batch
    const size_t per_batch = SZ_ATTN + 3 * SZ_Q + SZ_PART;

    int nb = (int)(ws_size / per_batch);
    if (nb < 1) nb = 1;
    if (nb > B_) nb = B_;

    char* ws        = (char*)d_ws;
    _Float16* attnE = (_Float16*)ws;
    char* q16       = ws + (size_t)nb * SZ_ATTN;
    char* kv16      = q16 + (size_t)nb * SZ_Q;
    char* vtb       = kv16 + (size_t)nb * SZ_Q;
    float2* part    = (float2*)(vtb + (size_t)nb * SZ_Q);

    for (int b0 = 0; b0 < B_; b0 += nb) {
        int cur = (B_ - b0 < nb) ? (B_ - b0) : nb;
        prep3<<<cur * 96, 256, 0, stream>>>(feat1, feat2, q16, kv16, vtb, b0, cur, cur * 24);
        qk6<<<cur * 16, 512, 0, stream>>>(q16, kv16, attnE, part, cur);
        pv11<<<cur * 18, 512, 0, stream>>>(attnE, vtb, part, gamma, feat1, out, b0, cur);
    }
}

// Round 19
// 126.071 us; speedup vs baseline: 1.1341x; 1.0102x over previous
//
#include <hip/hip_runtime.h>

// Problem constants: B=32, C=768, H=W=24 -> HW=576
#define B_  32
#define C_  768
#define HW_ 576

#define NCQ 18               // HW_/32 k-chunks (qk)
#define NCP 24               // C_/32 k-chunks (pv)

typedef _Float16 half8 __attribute__((ext_vector_type(8)));
typedef _Float16 half4 __attribute__((ext_vector_type(4)));
typedef float    f32x4 __attribute__((ext_vector_type(4)));

__device__ __forceinline__ void g2l16(const void* g, void* l) {
    __builtin_amdgcn_global_load_lds(
        (const __attribute__((address_space(1))) unsigned int*)g,
        (__attribute__((address_space(3))) unsigned int*)l, 16, 0, 0);
}

#define VM(N) asm volatile("s_waitcnt vmcnt(" #N ")" ::: "memory")

// attnE holds exp(S - mx_half) in fp16, LINEARIZED chunk-major:
//   elem index = ((bz*6 + strip)*24 + chunk)*4096 + row_in_strip*32 + col_in_chunk
// pv rescales by exp(mx_half - m_row)*gamma/s_row per (row, 96-col half).

// ---------------------------------------------------------------------------
// prep4: SINGLE DELTA vs round-18 prep3: q16/kv16 stores are COALESCED via
// LDS assembly. Block = (source, 128-strip, 32-row group): phase 1 reads
// 72KB sequential fp32, converts, scatters 8B half4 into LDS (k0 segments
// padded +16B -> <=2-way bank aliasing, free); phase 2 copies LDS->global as
// contiguous 2KB segments (1KB linear per wave). Output bytes identical.
// vt branch unchanged (aliases the same LDS).
// ---------------------------------------------------------------------------
__global__ __launch_bounds__(256) void prep4(const float* __restrict__ f1,
                                             const float* __restrict__ f2,
                                             char* __restrict__ q16,
                                             char* __restrict__ kv16,
                                             char* __restrict__ vt,
                                             int b0, int cur, int nst) {
    __shared__ __align__(16) char Lb[18 * 2064];   // 37,152 B
    const int bid = blockIdx.x;
    if (bid < nst) {
        // u in [0,48): sel = u&1 (0:f1->q16, 1:f2->kv16), rg = (u>>1)&3, ti = u>>3
        const int bz = bid % cur, u = bid / cur;
        const int sel = u & 1, rg = (u >> 1) & 3, ti = u >> 3;
        const float* s = (sel ? f2 : f1) + ((size_t)(b0 + bz) * C_ + ti * 128 + rg * 32) * HW_;
        char* d = (sel ? kv16 : q16) + ((size_t)(bz * 6 + ti)) * (NCQ * 8192) + rg * 2048;

        // phase 1: sequential reads, scattered LDS writes (staged layout,
        // k0-segment stride 2064 = 2048 + 16 pad)
        #pragma unroll
        for (int it = 0; it < 18; ++it) {
            int g     = it * 1024 + threadIdx.x * 4;   // float idx in 32x576 group
            int row_l = g / 576;
            int col   = g - row_l * 576;
            int row   = rg * 32 + row_l;
            int k0    = col >> 5, kk = col & 31;
            int x     = (kk >> 3) ^ ((row >> 1) & 3);
            int loff  = k0 * 2064 + row_l * 64 + x * 16 + (kk & 7) * 2;
            f32x4 v = *(const f32x4*)(s + g);
            half4 h;
            #pragma unroll
            for (int e = 0; e < 4; ++e) h[e] = (_Float16)v[e];
            *(half4*)(Lb + loff) = h;
        }
        __syncthreads();

        // phase 2: linear LDS read -> contiguous global stores (16B/lane)
        #pragma unroll
        for (int p = 0; p < 9; ++p) {
            int idx = p * 256 + threadIdx.x;           // 0..2303
            int k0  = idx >> 7;                        // segment (128 x 16B each)
            int wi  = idx & 127;
            *(f32x4*)(d + (size_t)k0 * 8192 + wi * 16) =
                *(const f32x4*)(Lb + k0 * 2064 + wi * 16);
        }
    } else {
        float* Vsh = (float*)Lb;                       // 25,728 B used
        int bid2 = bid - nst;
        const int bz = bid2 % cur, u = bid2 / cur;     // u in [0,72)
        int k0 = u / 3, tj = u % 3;
        int b  = b0 + bz;
        int t  = threadIdx.x;
        #pragma unroll
        for (int p = 0; p < 6; ++p) {
            int fidx = p * 256 + t;
            int dd = fidx / 48, c4 = fidx % 48;
            f32x4 v = *(const f32x4*)(f2 + ((size_t)b * C_ + k0 * 32 + dd) * HW_ + tj * 192 + c4 * 4);
            #pragma unroll
            for (int e = 0; e < 4; ++e) Vsh[dd * 201 + c4 * 4 + e] = v[e];
        }
        __syncthreads();
        char* ob = vt + ((size_t)(bz * 3 + tj) * NCP + k0) * 12288;
        #pragma unroll
        for (int p = 0; p < 3; ++p) {
            int o = p * 256 + t;
            int x = o & 3, n = o >> 2;
            int kc = x ^ ((n >> 1) & 3);
            half8 h;
            #pragma unroll
            for (int j = 0; j < 8; ++j) h[j] = (_Float16)Vsh[(kc * 8 + j) * 201 + n];
            *(half8*)(ob + o * 16) = h;
        }
    }
}

// ---------------------------------------------------------------------------
// qk6: S = q @ kv^T. Tile 192x192, 8 waves (4Mx2N), BK=32, ring-3, depth-2
// counted-vmcnt pipeline. Epilogue: per-(row,96-col-half) partials {mx,s} +
// attnE = fp16 exp(S - mx_half). (round-18 exact)
// ---------------------------------------------------------------------------
__global__ __launch_bounds__(512, 4) void qk6(const char* __restrict__ q16,
                                              const char* __restrict__ kv16,
                                              _Float16* __restrict__ attnE,
                                              float2* __restrict__ part,
                                              int cur) {
    __shared__ __align__(16) char S[3][24576];
    const int wg = blockIdx.x;
    const int bz = wg % cur, u = wg / cur;   // u in [0,16)
    const int ti = u >> 2, tj = u & 3;
    const int t = threadIdx.x, lane = t & 63, w = t >> 6;
    const int rsub = lane >> 2, cb = (lane & 3) * 16;

    const char *p0, *p1, *p2;
    int o0, o1, o2;
    {
        auto arow = [&](int l) {
            int gr = ti * 192 + 16 * l + rsub;
            return q16 + ((size_t)(bz * 6 + (gr >> 7)) * NCQ) * 8192 + (gr & 127) * 64 + cb;
        };
        auto brow = [&](int l) {
            int gd = tj * 192 + 16 * l + rsub;
            return kv16 + ((size_t)(bz * 6 + (gd >> 7)) * NCQ) * 8192 + (gd & 127) * 64 + cb;
        };
        if (w < 4) {
            p0 = arow(2 * w);     o0 = (2 * w) * 1024;
            p1 = arow(2 * w + 1); o1 = (2 * w + 1) * 1024;
            p2 = brow(8 + w);     o2 = 12288 + (8 + w) * 1024;
        } else {
            int v = w - 4;
            p0 = brow(2 * v);     o0 = 12288 + (2 * v) * 1024;
            p1 = brow(2 * v + 1); o1 = 12288 + (2 * v + 1) * 1024;
            p2 = arow(8 + v);     o2 = (8 + v) * 1024;
        }
    }

    const int wr = (w >> 1) * 48, wc = (w & 1) * 96;
    const int r16 = lane & 15, cg = lane >> 4;
    int offA[3], offB[6];
    #pragma unroll
    for (int m = 0; m < 3; ++m) {
        int ra = wr + m * 16 + r16;
        offA[m] = ra * 64 + ((cg ^ ((ra >> 1) & 3)) << 4);
    }
    #pragma unroll
    for (int n = 0; n < 6; ++n) {
        int rb = wc + n * 16 + r16;
        offB[n] = 12288 + rb * 64 + ((cg ^ ((rb >> 1) & 3)) << 4);
    }

    f32x4 acc[3][6] = {};

#define STG(SLOT) do {                          \
        char* sb_ = &S[SLOT][0];                \
        g2l16(p0, sb_ + o0);                    \
        g2l16(p1, sb_ + o1);                    \
        g2l16(p2, sb_ + o2);                    \
        p0 += 8192; p1 += 8192; p2 += 8192;     \
    } while (0)

    STG(0); STG(1);
    int rd = 0, st = 2;
    for (int c = 0; c < NCQ; ++c) {
        if (c + 2 < NCQ) {
            STG(st); st = (st == 2) ? 0 : st + 1;
            VM(6);
        } else if (c + 2 == NCQ) {
            VM(3);
        } else {
            VM(0);
        }
        __builtin_amdgcn_s_barrier();
        const char* sb = &S[rd][0];
        rd = (rd == 2) ? 0 : rd + 1;
        half8 a0 = *(const half8*)(sb + offA[0]);
        half8 a1 = *(const half8*)(sb + offA[1]);
        half8 a2 = *(const half8*)(sb + offA[2]);
        __builtin_amdgcn_s_setprio(1);
        #pragma unroll
        for (int n = 0; n < 6; ++n) {
            half8 bn = *(const half8*)(sb + offB[n]);
            acc[0][n] = __builtin_amdgcn_mfma_f32_16x16x32_f16(a0, bn, acc[0][n], 0, 0, 0);
            acc[1][n] = __builtin_amdgcn_mfma_f32_16x16x32_f16(a1, bn, acc[1][n], 0, 0, 0);
            acc[2][n] = __builtin_amdgcn_mfma_f32_16x16x32_f16(a2, bn, acc[2][n], 0, 0, 0);
        }
        __builtin_amdgcn_s_setprio(0);
        __builtin_amdgcn_s_barrier();
    }
#undef STG

    // --- partials first (captures mx per (m,rg)) ---
    const int half = w & 1;
    float mxv[3][4];                 // static-indexed only
    #pragma unroll
    for (int m = 0; m < 3; ++m)
        #pragma unroll
        for (int rg = 0; rg < 4; ++rg) {
            float mx = -1e30f;
            #pragma unroll
            for (int n = 0; n < 6; ++n) mx = fmaxf(mx, acc[m][n][rg]);
            #pragma unroll
            for (int o = 1; o < 16; o <<= 1) mx = fmaxf(mx, __shfl_xor(mx, o));
            mxv[m][rg] = mx;
            float s = 0.f;
            #pragma unroll
            for (int n = 0; n < 6; ++n) s += __expf(acc[m][n][rg] - mx);
            #pragma unroll
            for (int o = 1; o < 16; o <<= 1) s += __shfl_xor(s, o);
            if ((lane & 15) == 0) {
                int row = wr + m * 16 + (lane >> 4) * 4 + rg;
                part[((size_t)bz * C_ + ti * 192 + row) * 8 + tj * 2 + half] =
                    make_float2(mx, s);
            }
        }

    // --- attnE write: fp16 exp(S - mx_half), linearized chunk-major ---
    const int col = lane & 15, rbase = (lane >> 4) * 4;
    #pragma unroll
    for (int m = 0; m < 3; ++m)
        #pragma unroll
        for (int n = 0; n < 6; ++n)
            #pragma unroll
            for (int rg = 0; rg < 4; ++rg) {
                int grow = ti * 192 + wr + m * 16 + rbase + rg;
                int gcol = tj * 192 + wc + n * 16 + col;
                attnE[(((size_t)bz * 6 + (grow >> 7)) * NCP + (gcol >> 5)) * 4096
                      + (grow & 127) * 32 + (gcol & 31)] =
                    (_Float16)__expf(acc[m][n][rg] - mxv[m][rg]);
            }
}

// ---------------------------------------------------------------------------
// pv11: out = (gamma*P)@V + feat1. Paired chunks (12 unrolled phases),
// ring-4 of {A 8KB | B 12KB} slots, fp16 exp A-stream with per-(row,half)
// rescale. (round-18 exact)
// ---------------------------------------------------------------------------
__global__ __launch_bounds__(512, 4) void pv11(const _Float16* __restrict__ attnE,
                                               const char* __restrict__ vt,
                                               const float2* __restrict__ part,
                                               const float* __restrict__ gamma,
                                               const float* __restrict__ f1,
                                               float* __restrict__ out,
                                               int b0, int cur) {
    __shared__ __align__(16) char S[4][20480];   // per slot: A 8KB | B 12KB
    const int wg = blockIdx.x;
    const int bz = wg % cur, u = wg / cur;       // u in [0,18)
    const int ti = u / 3, tj = u % 3;
    const int t = threadIdx.x, lane = t & 63, w = t >> 6;
    const int rsub = lane >> 2, cbb = (lane & 3) * 16;

    const int r0 = t >> 2;
    const int g4 = t & 3;
    const char* srcA = (const char*)(attnE + (((size_t)bz * 6 + ti) * NCP) * 4096) + t * 16;
    const int aw0 = r0 * 64 + ((g4 ^ ((r0 >> 1) & 3)) << 4);

    float2 pm[8];
    float m_row, inv;
    {
        const float2* pr = part + ((size_t)bz * C_ + ti * 128 + r0) * 8;
        #pragma unroll
        for (int i = 0; i < 8; ++i) pm[i] = pr[i];
        float m = pm[0].x;
        #pragma unroll
        for (int i = 1; i < 8; ++i) m = fmaxf(m, pm[i].x);
        float s = 0.f;
        #pragma unroll
        for (int i = 0; i < 8; ++i) s += pm[i].y * __expf(pm[i].x - m);
        m_row = m;
        inv = gamma[0] / s;
    }

    const char* vbase = vt + ((size_t)(bz * 3 + tj) * NCP) * 12288;
    const char *pB0, *pB1;
    int ob0, ob1;
    if (w < 4) {
        pB0 = vbase + (32 * w + rsub) * 64 + cbb;          ob0 = 8192 + (32 * w) * 64;
        pB1 = vbase + (32 * w + 16 + rsub) * 64 + cbb;     ob1 = 8192 + (32 * w + 16) * 64;
    } else {
        pB0 = vbase + (128 + 16 * (w - 4) + rsub) * 64 + cbb;
        ob0 = 8192 + (128 + 16 * (w - 4)) * 64;
        pB1 = vbase; ob1 = 0;  // unused
    }

    const int wr = (w >> 2) * 64, wc = (w & 3) * 48;
    const int r16 = lane & 15, cg = lane >> 4;
    int offA[4], offB[3];
    #pragma unroll
    for (int m = 0; m < 4; ++m) {
        int ra = wr + m * 16 + r16;
        offA[m] = ra * 64 + ((cg ^ ((ra >> 1) & 3)) << 4);
    }
    #pragma unroll
    for (int n = 0; n < 3; ++n) {
        int rb = wc + n * 16 + r16;
        offB[n] = 8192 + rb * 64 + ((cg ^ ((rb >> 1) & 3)) << 4);
    }

    f32x4 acc[4][3] = {};
    half8 vaA, vaB;

#define STG_B(SLOT) do {                                  \
        g2l16(pB0, &S[SLOT][0] + ob0); pB0 += 12288;      \
        if (w < 4) { g2l16(pB1, &S[SLOT][0] + ob1); pB1 += 12288; } \
    } while (0)
#define LD_A(V) do { V = *(const half8*)srcA; srcA += 8192; } while (0)
#define WR_A(SLOT, V, H) do {                                          \
        const float fac_ = __expf(pm[H].x - m_row) * inv;              \
        half8 h_;                                                      \
        _Pragma("unroll")                                              \
        for (int e = 0; e < 8; ++e)                                    \
            h_[e] = (_Float16)((float)V[e] * fac_);                    \
        *(half8*)(&S[SLOT][0] + aw0) = h_;                             \
    } while (0)
#define MFMA_SLOT(SB) do {                                             \
        const char* sb_ = (SB);                                        \
        half8 a_[4], b_[3];                                            \
        _Pragma("unroll")                                              \
        for (int m = 0; m < 4; ++m) a_[m] = *(const half8*)(sb_ + offA[m]); \
        _Pragma("unroll")                                              \
        for (int n = 0; n < 3; ++n) b_[n] = *(const half8*)(sb_ + offB[n]); \
        _Pragma("unroll")                                              \
        for (int m = 0; m < 4; ++m)                                    \
            _Pragma("unroll")                                          \
            for (int n = 0; n < 3; ++n)                                \
                acc[m][n] = __builtin_amdgcn_mfma_f32_16x16x32_f16(a_[m], b_[n], acc[m][n], 0, 0, 0); \
    } while (0)

    LD_A(vaA);
    WR_A(0, vaA, 0);
    LD_A(vaB);
    WR_A(1, vaB, 0);
    STG_B(0); STG_B(1);
    LD_A(vaA);               // chunk 2
    LD_A(vaB);               // chunk 3

    #pragma unroll
    for (int p = 0; p < 12; ++p) {
        const int sa = (2 * p) & 3;
        asm volatile("s_waitcnt lgkmcnt(0)" ::: "memory");
        __builtin_amdgcn_s_barrier();
        if (p < 11) { STG_B((sa + 2) & 3); STG_B((sa + 3) & 3); }
        if (p < 11) { if (w < 4) VM(6); else VM(4); }
        else        { VM(0); }
        __builtin_amdgcn_s_barrier();

        __builtin_amdgcn_s_setprio(1);
        MFMA_SLOT(&S[sa][0]);
        MFMA_SLOT(&S[sa ^ 1][0]);
        __builtin_amdgcn_s_setprio(0);

        if (p < 11) {
            WR_A((sa + 2) & 3, vaA, (2 * p + 2) / 3);
            WR_A((sa + 3) & 3, vaB, (2 * p + 3) / 3);
            if (p < 10) {
                LD_A(vaA);
                LD_A(vaB);
            }
        }
    }
#undef MFMA_SLOT
#undef WR_A
#undef LD_A
#undef STG_B

    const int b = b0 + bz;
    const float* f1b = f1 + ((size_t)b * C_ + ti * 128) * HW_ + tj * 192;
    float*       ob  = out + ((size_t)b * C_ + ti * 128) * HW_ + tj * 192;
    const int col = lane & 15, rbase = (lane >> 4) * 4;
    #pragma unroll
    for (int m = 0; m < 4; ++m)
        #pragma unroll
        for (int n = 0; n < 3; ++n)
            #pragma unroll
            for (int rg = 0; rg < 4; ++rg) {
                int r2 = wr + m * 16 + rbase + rg;
                int c2 = wc + n * 16 + col;
                ob[(size_t)r2 * HW_ + c2] = acc[m][n][rg] + f1b[(size_t)r2 * HW_ + c2];
            }
}

// ---------------------------------------------------------------------------
extern "C" void kernel_launch(void* const* d_in, const int* in_sizes, int n_in,
                              void* d_out, int out_size, void* d_ws, size_t ws_size,
                              hipStream_t stream) {
    const float* feat1 = (const float*)d_in[0];
    const float* feat2 = (const float*)d_in[1];
    const float* gamma = (const float*)d_in[2];
    float* out = (float*)d_out;

    const size_t SZ_Q    = (size_t)C_ * HW_ * 2;      //   884,736 B/batch
    const size_t SZ_ATTN = (size_t)C_ * C_  * 2;      // 1,179,648 B/batch (fp16 exp)
    const size_t SZ_PART = (size_t)C_ * 8 * 8;        //    49,152 B/batch
    const size_t per_batch = SZ_ATTN + 3 * SZ_Q + SZ_PART;

    int nb = (int)(ws_size / per_batch);
    if (nb < 1) nb = 1;
    if (nb > B_) nb = B_;

    char* ws        = (char*)d_ws;
    _Float16* attnE = (_Float16*)ws;
    char* q16       = ws + (size_t)nb * SZ_ATTN;
    char* kv16      = q16 + (size_t)nb * SZ_Q;
    char* vtb       = kv16 + (size_t)nb * SZ_Q;
    float2* part    = (float2*)(vtb + (size_t)nb * SZ_Q);

    for (int b0 = 0; b0 < B_; b0 += nb) {
        int cur = (B_ - b0 < nb) ? (B_ - b0) : nb;
        prep4<<<cur * 120, 256, 0, stream>>>(feat1, feat2, q16, kv16, vtb, b0, cur, cur * 48);
        qk6<<<cur * 16, 512, 0, stream>>>(q16, kv16, attnE, part, cur);
        pv11<<<cur * 18, 512, 0, stream>>>(attnE, vtb, part, gamma, feat1, out, b0, cur);
    }
}